// Round 3
// baseline (667.320 us; speedup 1.0000x reference)
//
#include <hip/hip_runtime.h>
#include <hip/hip_fp16.h>

#define N_IN 200000
#define N_OUT 200000
#define K_VOL 27
#define M_PAIRS 100000
#define C_IN 64
#define C_OUT 64
#define NPAIRS (K_VOL * M_PAIRS)

#define MTILE 64
#define LDS_PAD 72   // 64+8 f16 elems -> 144B row stride, breaks bank aliasing, keeps 16B align

typedef __attribute__((ext_vector_type(4))) float floatx4;
typedef __attribute__((ext_vector_type(8))) short shortx8;
typedef __attribute__((ext_vector_type(8))) _Float16 halfx8;
typedef __attribute__((ext_vector_type(2))) _Float16 half2v;

// ---- workspace layout (bytes) ----
#define FEATS_OFF   0UL
#define FEATS_BYTES (200000UL * 64 * 2)             // 25,600,000 (f16)
#define WT_OFF      (FEATS_OFF + FEATS_BYTES)
#define WT_BYTES    (27UL * 64 * 64 * 2)            // 221,184 (f16, [k][o][c])
#define ACC_OFF     ((WT_OFF + WT_BYTES + 255UL) & ~255UL)
#define ACC_BYTES   (200000UL * 64 * 2)             // 25,600,000 (f16 accumulator)
#define WS_NEEDED   (ACC_OFF + ACC_BYTES)           // ~51.4 MB
#define WS_FALLBACK (WT_OFF + WT_BYTES)             // ~25.9 MB (round-1 path)

static __device__ __forceinline__ ushort f32_to_f16_bits(float f) {
    union { _Float16 h; ushort u; } cv;
    cv.h = (_Float16)f;
    return cv.u;
}

// packed f16 atomic add (global_atomic_pk_add_f16)
static __device__ __forceinline__ void atomic_pk_add_f16(ushort* addr, float lo, float hi) {
    half2v v;
    v[0] = (_Float16)lo;
    v[1] = (_Float16)hi;
#if defined(__has_builtin) && __has_builtin(__builtin_amdgcn_global_atomic_fadd_v2f16)
    typedef half2v __attribute__((address_space(1))) *as1p;
    __builtin_amdgcn_global_atomic_fadd_v2f16((as1p)(unsigned long long)addr, v);
#else
    unsafeAtomicAdd((__half2*)addr, *(__half2*)&v);
#endif
}

// ---------------- prep ----------------
__global__ void cvt_feats_kernel(const float* __restrict__ src, ushort* __restrict__ dst, int n4) {
    int i = blockIdx.x * blockDim.x + threadIdx.x;
    if (i >= n4) return;
    float4 v = ((const float4*)src)[i];
    ushort4 o;
    o.x = f32_to_f16_bits(v.x); o.y = f32_to_f16_bits(v.y);
    o.z = f32_to_f16_bits(v.z); o.w = f32_to_f16_bits(v.w);
    ((ushort4*)dst)[i] = o;
}

// kernel[k][c][o] fp32 -> wt[k][o][c] f16
__global__ void cvt_wt_kernel(const float* __restrict__ w, ushort* __restrict__ wt) {
    int idx = blockIdx.x * blockDim.x + threadIdx.x;
    if (idx >= K_VOL * C_IN * C_OUT) return;
    int k   = idx >> 12;
    int rem = idx & 4095;
    int c   = rem >> 6;
    int o   = rem & 63;
    wt[(k << 12) + (o << 6) + c] = f32_to_f16_bits(w[idx]);
}

// ---------------- main: gather -> f16 MFMA -> pk_add_f16 scatter ----------------
__launch_bounds__(256, 4)
__global__ void spconv_f16_kernel(const ushort* __restrict__ feats,  // [N_IN][64] f16
                                  const ushort* __restrict__ wt,     // [K][o][c] f16
                                  const int* __restrict__ imap,
                                  const int* __restrict__ omap,
                                  ushort* __restrict__ accum) {      // [N_OUT][64] f16
    __shared__ ushort Asm[MTILE * LDS_PAD];
    __shared__ ushort Wsm[C_OUT * LDS_PAD];
    __shared__ int omap_s[MTILE];

    const int k   = blockIdx.y;
    const int m0  = blockIdx.x * MTILE;
    const int tid = threadIdx.x;
    const int kM  = k * M_PAIRS;

    #pragma unroll
    for (int p = 0; p < 2; ++p) {
        int cid = tid + p * 256;
        int row = cid >> 3;
        int ch  = cid & 7;
        *(shortx8*)&Wsm[row * LDS_PAD + ch * 8] =
            *(const shortx8*)&wt[(k << 12) + row * 64 + ch * 8];
    }
    #pragma unroll
    for (int p = 0; p < 2; ++p) {
        int cid = tid + p * 256;
        int row = cid >> 3;
        int ch  = cid & 7;
        int m   = m0 + row;
        shortx8 v = {0, 0, 0, 0, 0, 0, 0, 0};
        if (m < M_PAIRS) {
            int g = imap[kM + m];
            v = *(const shortx8*)&feats[(g << 6) + ch * 8];
        }
        *(shortx8*)&Asm[row * LDS_PAD + ch * 8] = v;
    }
    if (tid < MTILE) {
        int m = m0 + tid;
        omap_s[tid] = (m < M_PAIRS) ? omap[kM + m] : -1;
    }
    __syncthreads();

    const int wave = tid >> 6;
    const int lane = tid & 63;
    const int quad = lane >> 4;
    const int l16  = lane & 15;
    const int rbase = wave * 16;
    const bool even = (l16 & 1) == 0;

    // A[m=l16][k=quad*8+j]
    const halfx8 a0 = *(const halfx8*)&Asm[(rbase + l16) * LDS_PAD + quad * 8];
    const halfx8 a1 = *(const halfx8*)&Asm[(rbase + l16) * LDS_PAD + 32 + quad * 8];

    #pragma unroll
    for (int ct = 0; ct < 4; ++ct) {
        const halfx8 b0 = *(const halfx8*)&Wsm[(ct * 16 + l16) * LDS_PAD + quad * 8];
        const halfx8 b1 = *(const halfx8*)&Wsm[(ct * 16 + l16) * LDS_PAD + 32 + quad * 8];
        floatx4 acc = {0.f, 0.f, 0.f, 0.f};
        acc = __builtin_amdgcn_mfma_f32_16x16x32_f16(a0, b0, acc, 0, 0, 0);
        acc = __builtin_amdgcn_mfma_f32_16x16x32_f16(a1, b1, acc, 0, 0, 0);

        // C layout: col = ct*16 + l16, row = rbase + quad*4 + r.
        // Pack adjacent columns (lane pair) into one pk_add_f16:
        //   even lane handles rows r=0,1 ; odd lane rows r=2,3.
        float p0 = __shfl_xor(acc[0], 1, 64);
        float p1 = __shfl_xor(acc[1], 1, 64);
        float p2 = __shfl_xor(acc[2], 1, 64);
        float p3 = __shfl_xor(acc[3], 1, 64);

        const int colb = ct * 16 + (l16 & ~1);
        float lo0, hi0, lo1, hi1;
        int r0;
        if (even) { r0 = 0; lo0 = acc[0]; hi0 = p0; lo1 = acc[1]; hi1 = p1; }
        else      { r0 = 2; lo0 = p2;     hi0 = acc[2]; lo1 = p3; hi1 = acc[3]; }

        int row0 = rbase + quad * 4 + r0;
        int o0 = omap_s[row0];
        int o1 = omap_s[row0 + 1];
        if (o0 >= 0) atomic_pk_add_f16(&accum[(o0 << 6) + colb], lo0, hi0);
        if (o1 >= 0) atomic_pk_add_f16(&accum[(o1 << 6) + colb], lo1, hi1);
    }
}

// ---------------- finalize: f16 accum + bias -> fp32 out ----------------
__global__ void finalize_kernel(const ushort* __restrict__ accum,
                                const float* __restrict__ bias,
                                float* __restrict__ out, int n8) {
    int i = blockIdx.x * blockDim.x + threadIdx.x;
    if (i >= n8) return;
    halfx8 h = *(const halfx8*)&accum[(size_t)i * 8];
    int c = (i * 8) & 63;
    float4 b0 = *(const float4*)(bias + c);
    float4 b1 = *(const float4*)(bias + c + 4);
    float4 o0, o1;
    o0.x = (float)h[0] + b0.x; o0.y = (float)h[1] + b0.y;
    o0.z = (float)h[2] + b0.z; o0.w = (float)h[3] + b0.w;
    o1.x = (float)h[4] + b1.x; o1.y = (float)h[5] + b1.y;
    o1.z = (float)h[6] + b1.z; o1.w = (float)h[7] + b1.w;
    ((float4*)out)[(size_t)i * 2]     = o0;
    ((float4*)out)[(size_t)i * 2 + 1] = o1;
}

// ---------------- fallback (fp32 atomics into d_out, f16 MFMA) ----------------
__global__ void init_bias_kernel(const float* __restrict__ bias, float* __restrict__ out, int n4) {
    int i = blockIdx.x * blockDim.x + threadIdx.x;
    if (i >= n4) return;
    int c = (i * 4) & 63;
    float4 b = *(const float4*)(bias + c);
    ((float4*)out)[i] = b;
}

__launch_bounds__(256, 4)
__global__ void spconv_push_f32_kernel(const ushort* __restrict__ feats,
                                       const ushort* __restrict__ wt,
                                       const int* __restrict__ imap,
                                       const int* __restrict__ omap,
                                       float* __restrict__ out) {
    __shared__ ushort Asm[MTILE * LDS_PAD];
    __shared__ ushort Wsm[C_OUT * LDS_PAD];
    __shared__ int omap_s[MTILE];

    const int k   = blockIdx.y;
    const int m0  = blockIdx.x * MTILE;
    const int tid = threadIdx.x;
    const int kM  = k * M_PAIRS;

    #pragma unroll
    for (int p = 0; p < 2; ++p) {
        int cid = tid + p * 256;
        int row = cid >> 3;
        int ch  = cid & 7;
        *(shortx8*)&Wsm[row * LDS_PAD + ch * 8] =
            *(const shortx8*)&wt[(k << 12) + row * 64 + ch * 8];
    }
    #pragma unroll
    for (int p = 0; p < 2; ++p) {
        int cid = tid + p * 256;
        int row = cid >> 3;
        int ch  = cid & 7;
        int m   = m0 + row;
        shortx8 v = {0, 0, 0, 0, 0, 0, 0, 0};
        if (m < M_PAIRS) {
            int g = imap[kM + m];
            v = *(const shortx8*)&feats[(g << 6) + ch * 8];
        }
        *(shortx8*)&Asm[row * LDS_PAD + ch * 8] = v;
    }
    if (tid < MTILE) {
        int m = m0 + tid;
        omap_s[tid] = (m < M_PAIRS) ? omap[kM + m] : -1;
    }
    __syncthreads();

    const int wave = tid >> 6;
    const int lane = tid & 63;
    const int quad = lane >> 4;
    const int l16  = lane & 15;
    const int rbase = wave * 16;

    const halfx8 a0 = *(const halfx8*)&Asm[(rbase + l16) * LDS_PAD + quad * 8];
    const halfx8 a1 = *(const halfx8*)&Asm[(rbase + l16) * LDS_PAD + 32 + quad * 8];

    #pragma unroll
    for (int ct = 0; ct < 4; ++ct) {
        const halfx8 b0 = *(const halfx8*)&Wsm[(ct * 16 + l16) * LDS_PAD + quad * 8];
        const halfx8 b1 = *(const halfx8*)&Wsm[(ct * 16 + l16) * LDS_PAD + 32 + quad * 8];
        floatx4 acc = {0.f, 0.f, 0.f, 0.f};
        acc = __builtin_amdgcn_mfma_f32_16x16x32_f16(a0, b0, acc, 0, 0, 0);
        acc = __builtin_amdgcn_mfma_f32_16x16x32_f16(a1, b1, acc, 0, 0, 0);
        const int col = ct * 16 + l16;
        #pragma unroll
        for (int r = 0; r < 4; ++r) {
            int rl = rbase + quad * 4 + r;
            int orow = omap_s[rl];
            if (orow >= 0) atomicAdd(&out[(orow << 6) + col], acc[r]);
        }
    }
}

extern "C" void kernel_launch(void* const* d_in, const int* in_sizes, int n_in,
                              void* d_out, int out_size, void* d_ws, size_t ws_size,
                              hipStream_t stream) {
    const float* in_feats = (const float*)d_in[0];
    const float* kernelw  = (const float*)d_in[1];
    const float* bias     = (const float*)d_in[2];
    const int*   imap     = (const int*)d_in[3];
    const int*   omap     = (const int*)d_in[4];
    float* out = (float*)d_out;

    char* ws = (char*)d_ws;
    ushort* feats_h = (ushort*)(ws + FEATS_OFF);
    ushort* wt_h    = (ushort*)(ws + WT_OFF);

    int n4 = N_IN * C_IN / 4;
    cvt_feats_kernel<<<(n4 + 255) / 256, 256, 0, stream>>>(in_feats, feats_h, n4);
    cvt_wt_kernel<<<(K_VOL * C_IN * C_OUT + 255) / 256, 256, 0, stream>>>(kernelw, wt_h);

    dim3 grid((M_PAIRS + MTILE - 1) / MTILE, K_VOL);

    if (ws_size >= WS_NEEDED) {
        ushort* accum = (ushort*)(ws + ACC_OFF);
        hipMemsetAsync(accum, 0, ACC_BYTES, stream);   // f16 +0.0 == 0x0000
        spconv_f16_kernel<<<grid, 256, 0, stream>>>(feats_h, wt_h, imap, omap, accum);
        int n8 = N_OUT * C_OUT / 8;
        finalize_kernel<<<(n8 + 255) / 256, 256, 0, stream>>>(accum, bias, out, n8);
    } else {
        int o4 = N_OUT * C_OUT / 4;
        init_bias_kernel<<<(o4 + 255) / 256, 256, 0, stream>>>(bias, out, o4);
        spconv_push_f32_kernel<<<grid, 256, 0, stream>>>(feats_h, wt_h, imap, omap, out);
    }
}